// Round 7
// baseline (523.157 us; speedup 1.0000x reference)
//
#include <hip/hip_runtime.h>
#include <hip/hip_bf16.h>
#include <stdint.h>

#define NDIM 3072
#define BATCHN 8192
#define KTOP 16.0f
#define NITER 50

// ---- GEMM geometry: BM=BN=128, BK=32, 4-slot deep-pipelined LDS ----
#define BM 128
#define BN 128
#define BK 32
#define NT (NDIM / BK)          // 96 K-tiles
#define SLOT_BYTES 16384        // A 8KB + B 8KB
#define ABYTES 8192

typedef __attribute__((ext_vector_type(8))) short short8;
typedef __attribute__((ext_vector_type(4))) float floatx4;
typedef __attribute__((ext_vector_type(4))) unsigned short ushortx4;

__device__ inline unsigned short f2bf(float f) {
    __hip_bfloat16 h = __float2bfloat16(f);
    return *reinterpret_cast<unsigned short*>(&h);
}

// ---------------- K1: Dykstra soft-topk, reduced to scalar-D recursion ----------------
__global__ void dykstra_kernel(const float* __restrict__ alpha, float* __restrict__ a_out) {
    const int lane = threadIdx.x;  // 64 threads
    float z[48];
#pragma unroll
    for (int e = 0; e < 48; ++e) z[e] = alpha[e * 64 + lane] / 0.01f;
    float S = 0.f;
#pragma unroll
    for (int e = 0; e < 48; ++e) S += z[e];
#pragma unroll
    for (int m = 1; m < 64; m <<= 1) S += __shfl_xor(S, m, 64);

    float D = 0.f;
    for (int it = 0; it < NITER; ++it) {
        D += (KTOP - S) / (float)NDIM;
        float s2 = 0.f;
#pragma unroll
        for (int e = 0; e < 48; ++e) {
            float v = z[e] + D;
            v = v < 0.f ? 0.f : (v > 1.f ? 1.f : v);
            s2 += v;
        }
        S = s2;
#pragma unroll
        for (int m = 1; m < 64; m <<= 1) S += __shfl_xor(S, m, 64);
    }
#pragma unroll
    for (int e = 0; e < 48; ++e) {
        float v = z[e] + D;
        v = v < 0.f ? 0.f : (v > 1.f ? 1.f : v);
        a_out[e * 64 + lane] = v;
    }
}

// ---------------- K2: W[r,c] = a[(r-c)%n] * V[(r-c)%n, c] as bf16 (vectorized) ----------------
__global__ __launch_bounds__(256) void build_w(const float* __restrict__ V,
                                               const float* __restrict__ a,
                                               unsigned short* __restrict__ W) {
    __shared__ float Vs[128][64];
    __shared__ float as_[128];
    const int tid = threadIdx.x;
    const int c0 = blockIdx.x * 64;
    const int r0 = blockIdx.y * 64;
    int ib = r0 - c0 - 63;
    ib %= NDIM; if (ib < 0) ib += NDIM;

    if (tid < 128) {
        int i = ib + tid; if (i >= NDIM) i -= NDIM;
        as_[tid] = a[i];
    }
#pragma unroll
    for (int it = 0; it < 8; ++it) {
        int idx = it * 256 + tid;          // float4 units, 0..2047
        int d = idx >> 4;                  // 0..127
        int c4 = (idx & 15) * 4;
        int i = ib + d; if (i >= NDIM) i -= NDIM;
        *(floatx4*)&Vs[d][c4] = *(const floatx4*)&V[(size_t)i * NDIM + c0 + c4];
    }
    __syncthreads();

    const int c4 = (tid & 15) * 4;
    const int rr0 = tid >> 4;              // 0..15
#pragma unroll
    for (int p = 0; p < 4; ++p) {
        int rr = p * 16 + rr0;
        ushortx4 o;
#pragma unroll
        for (int j = 0; j < 4; ++j) {
            int cc = c4 + j;
            int d = rr - cc + 63;          // in [0,126]
            o[j] = f2bf(as_[d] * Vs[d][cc]);
        }
        *(ushortx4*)&W[(size_t)(r0 + rr) * NDIM + (c0 + c4)] = o;
    }
}

// ---------------- K3: x f32 -> bf16 ----------------
__global__ void convert_x(const float* __restrict__ x, unsigned short* __restrict__ xb, int n) {
    int i = (blockIdx.x * blockDim.x + threadIdx.x) * 4;
    const int stride = gridDim.x * blockDim.x * 4;
    for (; i < n; i += stride) {
        floatx4 v = *(const floatx4*)(x + i);
        ushortx4 o;
        o[0] = f2bf(v[0]); o[1] = f2bf(v[1]); o[2] = f2bf(v[2]); o[3] = f2bf(v[3]);
        *(ushortx4*)(xb + i) = o;
    }
}

// ---------------- K4: deep-pipelined bf16 GEMM, C[M,N] = A * B^T ----------------
// LDS layout per slot: 8 A-frag blocks (1KB each, lane-ordered) + 8 B-frag blocks.
// Frag block b holds rows b*16..b*16+15 x 32 k, stored so byte lane*16 = the exact
// 16B the MFMA lane needs -> ds_read_b128 at base+lane*16 is linear, 0 conflicts.
// Pipeline: stage tile T+3 while computing T; counted vmcnt(8) per phase (tail 4->0);
// raw s_barrier (no vmcnt drain); setprio around the MFMA cluster.
__global__ __launch_bounds__(256, 2) void gemm_bt(const unsigned short* __restrict__ A,
                                                  const unsigned short* __restrict__ B,
                                                  float* __restrict__ C) {
    __shared__ __align__(16) char lds[4 * SLOT_BYTES];   // 64 KB

    // XCD swizzle, grid 1536 (div by 8): same-XCD blocks share tn -> B panel L2-resident
    const int bid = blockIdx.x;
    const int swz = (bid & 7) * 192 + (bid >> 3);
    const int tm = swz & 63;      // 64 M tiles
    const int tn = swz >> 6;      // 24 N tiles
    const int m0 = tm * BM, n0 = tn * BN;

    const int tid = threadIdx.x;
    const int lane = tid & 63;
    const int wid = tid >> 6;     // 4 waves, 2x2
    const int wm = wid >> 1, wn = wid & 1;

    const unsigned short* Ab = A + (size_t)m0 * NDIM;
    const unsigned short* Bb = B + (size_t)n0 * NDIM;

    // staging decomposition: thread covers (block = r*4 + tid>>6, row = lane&15, k8 = lane>>4)
    const int sblk = tid >> 6;
    const int srow = lane & 15;
    const int scol = (lane >> 4) * 8;

    floatx4 acc[4][4];
#pragma unroll
    for (int i = 0; i < 4; ++i)
#pragma unroll
        for (int j = 0; j < 4; ++j) acc[i][j] = {0.f, 0.f, 0.f, 0.f};

    auto STAGE = [&](int T) {
        char* sb = lds + (T & 3) * SLOT_BYTES;
        const int kt = T * BK;
#pragma unroll
        for (int r = 0; r < 2; ++r) {
            const unsigned short* g = Ab + (size_t)((r * 4 + sblk) * 16 + srow) * NDIM + kt + scol;
            __builtin_amdgcn_global_load_lds(
                (const __attribute__((address_space(1))) unsigned int*)g,
                (__attribute__((address_space(3))) unsigned int*)(sb + r * 4096 + tid * 16),
                16, 0, 0);
        }
#pragma unroll
        for (int r = 0; r < 2; ++r) {
            const unsigned short* g = Bb + (size_t)((r * 4 + sblk) * 16 + srow) * NDIM + kt + scol;
            __builtin_amdgcn_global_load_lds(
                (const __attribute__((address_space(1))) unsigned int*)g,
                (__attribute__((address_space(3))) unsigned int*)(sb + ABYTES + r * 4096 + tid * 16),
                16, 0, 0);
        }
    };

    // prologue: stage tiles 0..2, ensure tile 0 landed collectively
    STAGE(0); STAGE(1); STAGE(2);
    asm volatile("s_waitcnt vmcnt(8)" ::: "memory");
    asm volatile("s_barrier" ::: "memory");

    for (int T = 0; T < NT; ++T) {
        const char* sb = lds + (T & 3) * SLOT_BYTES;
        short8 af[4], bf[4];
#pragma unroll
        for (int mi = 0; mi < 4; ++mi)
            af[mi] = *(const short8*)(sb + (wm * 4 + mi) * 1024 + lane * 16);
#pragma unroll
        for (int ni = 0; ni < 4; ++ni)
            bf[ni] = *(const short8*)(sb + ABYTES + (wn * 4 + ni) * 1024 + lane * 16);

        if (T + 3 < NT) STAGE(T + 3);   // writes slot (T-1)&3 — freed at phase T-1's closing barrier

        if (T < NT - 3)       { asm volatile("s_waitcnt vmcnt(8)" ::: "memory"); }  // tile T+1 landed
        else if (T == NT - 3) { asm volatile("s_waitcnt vmcnt(4)" ::: "memory"); }
        else if (T == NT - 2) { asm volatile("s_waitcnt vmcnt(0)" ::: "memory"); }
        asm volatile("s_barrier" ::: "memory");   // make the vmcnt guarantee collective

        __builtin_amdgcn_s_setprio(1);
#pragma unroll
        for (int mi = 0; mi < 4; ++mi)
#pragma unroll
            for (int ni = 0; ni < 4; ++ni)
                acc[mi][ni] = __builtin_amdgcn_mfma_f32_16x16x32_bf16(af[mi], bf[ni], acc[mi][ni], 0, 0, 0);
        __builtin_amdgcn_s_setprio(0);
        asm volatile("s_barrier" ::: "memory");   // all waves done with slot T before it is restaged
    }

    // epilogue: C/D layout col = lane&15, row = (lane>>4)*4 + reg  [verified round 3]
#pragma unroll
    for (int mi = 0; mi < 4; ++mi)
#pragma unroll
        for (int ni = 0; ni < 4; ++ni)
#pragma unroll
            for (int rg = 0; rg < 4; ++rg) {
                int rr = m0 + wm * 64 + mi * 16 + (lane >> 4) * 4 + rg;
                int cc = n0 + wn * 64 + ni * 16 + (lane & 15);
                C[(size_t)rr * NDIM + cc] = acc[mi][ni][rg];
            }
}

extern "C" void kernel_launch(void* const* d_in, const int* in_sizes, int n_in,
                              void* d_out, int out_size, void* d_ws, size_t ws_size,
                              hipStream_t stream) {
    const float* x     = (const float*)d_in[0];   // [8192][3072] f32
    const float* V     = (const float*)d_in[1];   // [3072][3072] f32
    const float* alpha = (const float*)d_in[2];   // [3072] f32
    float* out = (float*)d_out;                   // [8192][3072] f32

    // ws layout: a[3072] f32 | x_bf16 [8192*3072] | W_bf16 [3072*3072]
    float* a_ws = (float*)d_ws;
    unsigned short* xb = (unsigned short*)((char*)d_ws + 16384);
    unsigned short* Wb = (unsigned short*)((char*)d_ws + 16384 + (size_t)BATCHN * NDIM * 2);

    hipLaunchKernelGGL(dykstra_kernel, dim3(1), dim3(64), 0, stream, alpha, a_ws);
    hipLaunchKernelGGL(build_w, dim3(NDIM / 64, NDIM / 64), dim3(256), 0, stream, V, a_ws, Wb);
    hipLaunchKernelGGL(convert_x, dim3(2048), dim3(256), 0, stream, x, xb, BATCHN * NDIM);
    hipLaunchKernelGGL(gemm_bt, dim3((BATCHN / BM) * (NDIM / BN)), dim3(256), 0, stream,
                       xb, Wb, out);
}

// Round 9
// 455.434 us; speedup vs baseline: 1.1487x; 1.1487x over previous
//
#include <hip/hip_runtime.h>
#include <hip/hip_bf16.h>
#include <stdint.h>

#define NDIM 3072
#define BATCHN 8192
#define KTOP 16.0f
#define NITER 50

// ---- GEMM geometry: BM=256, BN=128, BK=64, 3-buffer stage-2-ahead pipeline ----
#define BM 256
#define BN 128
#define BK 64
#define NKT (NDIM / BK)         // 48 K-tiles
#define A_BYTES 32768           // 256 x 64 bf16
#define B_BYTES 16384           // 128 x 64 bf16
#define BUF_BYTES 49152         // A + B per K-tile
// LDS total: 3 * 48 KB = 144 KB (1 block/CU, 8 waves)

typedef __attribute__((ext_vector_type(8))) short short8;
typedef __attribute__((ext_vector_type(4))) float floatx4;
typedef __attribute__((ext_vector_type(4))) unsigned short ushortx4;

__device__ inline unsigned short f2bf(float f) {
    __hip_bfloat16 h = __float2bfloat16(f);
    return *reinterpret_cast<unsigned short*>(&h);
}

// ---------------- K1: Dykstra soft-topk, reduced to scalar-D recursion ----------------
__global__ void dykstra_kernel(const float* __restrict__ alpha, float* __restrict__ a_out) {
    const int lane = threadIdx.x;  // 64 threads
    float z[48];
#pragma unroll
    for (int e = 0; e < 48; ++e) z[e] = alpha[e * 64 + lane] / 0.01f;
    float S = 0.f;
#pragma unroll
    for (int e = 0; e < 48; ++e) S += z[e];
#pragma unroll
    for (int m = 1; m < 64; m <<= 1) S += __shfl_xor(S, m, 64);

    float D = 0.f;
    for (int it = 0; it < NITER; ++it) {
        D += (KTOP - S) / (float)NDIM;
        float s2 = 0.f;
#pragma unroll
        for (int e = 0; e < 48; ++e) {
            float v = z[e] + D;
            v = v < 0.f ? 0.f : (v > 1.f ? 1.f : v);
            s2 += v;
        }
        S = s2;
#pragma unroll
        for (int m = 1; m < 64; m <<= 1) S += __shfl_xor(S, m, 64);
    }
#pragma unroll
    for (int e = 0; e < 48; ++e) {
        float v = z[e] + D;
        v = v < 0.f ? 0.f : (v > 1.f ? 1.f : v);
        a_out[e * 64 + lane] = v;
    }
}

// ---------------- K2: W[r,c] = a[(r-c)%n] * V[(r-c)%n, c] as bf16 (vectorized) ----------------
__global__ __launch_bounds__(256) void build_w(const float* __restrict__ V,
                                               const float* __restrict__ a,
                                               unsigned short* __restrict__ W) {
    __shared__ float Vs[128][64];
    __shared__ float as_[128];
    const int tid = threadIdx.x;
    const int c0 = blockIdx.x * 64;
    const int r0 = blockIdx.y * 64;
    int ib = r0 - c0 - 63;
    ib %= NDIM; if (ib < 0) ib += NDIM;

    if (tid < 128) {
        int i = ib + tid; if (i >= NDIM) i -= NDIM;
        as_[tid] = a[i];
    }
#pragma unroll
    for (int it = 0; it < 8; ++it) {
        int idx = it * 256 + tid;          // float4 units, 0..2047
        int d = idx >> 4;                  // 0..127
        int c4 = (idx & 15) * 4;
        int i = ib + d; if (i >= NDIM) i -= NDIM;
        *(floatx4*)&Vs[d][c4] = *(const floatx4*)&V[(size_t)i * NDIM + c0 + c4];
    }
    __syncthreads();

    const int c4 = (tid & 15) * 4;
    const int rr0 = tid >> 4;              // 0..15
#pragma unroll
    for (int p = 0; p < 4; ++p) {
        int rr = p * 16 + rr0;
        ushortx4 o;
#pragma unroll
        for (int j = 0; j < 4; ++j) {
            int cc = c4 + j;
            int d = rr - cc + 63;          // in [0,126]
            o[j] = f2bf(as_[d] * Vs[d][cc]);
        }
        *(ushortx4*)&W[(size_t)(r0 + rr) * NDIM + (c0 + c4)] = o;
    }
}

// ---------------- K3: x f32 -> bf16 ----------------
__global__ void convert_x(const float* __restrict__ x, unsigned short* __restrict__ xb, int n) {
    int i = (blockIdx.x * blockDim.x + threadIdx.x) * 4;
    const int stride = gridDim.x * blockDim.x * 4;
    for (; i < n; i += stride) {
        floatx4 v = *(const floatx4*)(x + i);
        ushortx4 o;
        o[0] = f2bf(v[0]); o[1] = f2bf(v[1]); o[2] = f2bf(v[2]); o[3] = f2bf(v[3]);
        *(ushortx4*)(xb + i) = o;
    }
}

// ---------------- K4: 3-buffer stage-2-ahead bf16 GEMM, C[M,N] = A * B^T ----------------
// LDS per K-tile buffer: A as 32 lane-ordered 1KB cells (block b=0..15, kk=0..1),
// B as 16 cells. Cell (b,kk): lane l holds row b*16+(l&15), k kk*32+(l>>4)*8 ->
// every ds_read_b128 is base+lane*16 (linear, 0 conflicts — verified Round 7).
// Pipeline: while reading buf t%3, stage K-tile t+2 into buf (t+2)%3 (never the
// read or landing buffer). vmcnt(6) once per K-tile: newest 6 outstanding loads
// are t+2's, so t+1's are landed before its reads. Tail: vmcnt(0) at t=NKT-2.
__global__ __launch_bounds__(512, 2) void gemm_bt(const unsigned short* __restrict__ A,
                                                  const unsigned short* __restrict__ B,
                                                  float* __restrict__ C) {
    __shared__ __align__(16) char lds[3 * BUF_BYTES];   // 144 KB

    // XCD-chunked swizzle, tn-fastest (Round 3's low-FETCH ordering). 768 % 8 == 0.
    const int bid = blockIdx.x;
    const int swz = (bid & 7) * 96 + (bid >> 3);
    const int tm = swz / 24, tn = swz % 24;     // 32 x 24 tiles
    const int m0 = tm * BM, n0 = tn * BN;

    const int tid = threadIdx.x;
    const int lane = tid & 63;
    const int wid = tid >> 6;     // 8 waves: 4 (M) x 2 (N)
    const int wm = wid >> 1;      // 0..3 -> 64 rows each
    const int wn = wid & 1;       // 0..1 -> 64 cols each

    const unsigned short* Ab = A + (size_t)m0 * NDIM;
    const unsigned short* Bb = B + (size_t)n0 * NDIM;

    auto stageA = [&](char* sw, int kt, int i) {   // i in 0..3, cell c = wid*4+i
        int c = wid * 4 + i;
        int b = c >> 1, kk = c & 1;
        const unsigned short* g = Ab + (size_t)(b * 16 + (lane & 15)) * NDIM + kt + kk * 32 + (lane >> 4) * 8;
        __builtin_amdgcn_global_load_lds(
            (const __attribute__((address_space(1))) unsigned int*)g,
            (__attribute__((address_space(3))) unsigned int*)(sw + c * 1024 + lane * 16),
            16, 0, 0);
    };
    auto stageB = [&](char* sw, int kt, int i) {   // i in 0..1, cell c = wid*2+i
        int c = wid * 2 + i;
        int b = c >> 1, kk = c & 1;
        const unsigned short* g = Bb + (size_t)(b * 16 + (lane & 15)) * NDIM + kt + kk * 32 + (lane >> 4) * 8;
        __builtin_amdgcn_global_load_lds(
            (const __attribute__((address_space(1))) unsigned int*)g,
            (__attribute__((address_space(3))) unsigned int*)(sw + A_BYTES + c * 1024 + lane * 16),
            16, 0, 0);
    };

    floatx4 acc[4][4];
#pragma unroll
    for (int i = 0; i < 4; ++i)
#pragma unroll
        for (int j = 0; j < 4; ++j) acc[i][j] = {0.f, 0.f, 0.f, 0.f};

    // prologue: stage K-tiles 0 and 1 (6 loads/wave each); wait K-tile 0 landed.
    {
        char* s0 = lds;
        char* s1 = lds + BUF_BYTES;
#pragma unroll
        for (int i = 0; i < 4; ++i) stageA(s0, 0, i);
        stageB(s0, 0, 0); stageB(s0, 0, 1);
#pragma unroll
        for (int i = 0; i < 4; ++i) stageA(s1, BK, i);
        stageB(s1, BK, 0); stageB(s1, BK, 1);
        asm volatile("s_waitcnt vmcnt(6)" ::: "memory");
        asm volatile("s_barrier" ::: "memory");
    }

    int rb = 0;   // read buffer = t % 3
    for (int t = 0; t < NKT; ++t) {
        const char* sb = lds + rb * BUF_BYTES;
        int wbi = rb - 1; if (wbi < 0) wbi += 3;          // (t+2) % 3
        char* sw = lds + wbi * BUF_BYTES;
        const int kt2 = (t + 2) * BK;
        const bool do_stage = (t + 2) < NKT;

        // ---- phase 1: read A-set + B-low; stage 3; MFMA n=0,1 ----
        short8 af[4][2], bf[2][2];
#pragma unroll
        for (int m = 0; m < 4; ++m)
#pragma unroll
            for (int kk = 0; kk < 2; ++kk)
                af[m][kk] = *(const short8*)(sb + (wm * 4 + m) * 2048 + kk * 1024 + lane * 16);
#pragma unroll
        for (int n = 0; n < 2; ++n)
#pragma unroll
            for (int kk = 0; kk < 2; ++kk)
                bf[n][kk] = *(const short8*)(sb + A_BYTES + (wn * 4 + n) * 2048 + kk * 1024 + lane * 16);
        if (do_stage) { stageA(sw, kt2, 0); stageA(sw, kt2, 1); stageA(sw, kt2, 2); }
        asm volatile("s_barrier" ::: "memory");
        __builtin_amdgcn_s_setprio(1);
#pragma unroll
        for (int m = 0; m < 4; ++m)
#pragma unroll
            for (int n = 0; n < 2; ++n)
#pragma unroll
                for (int kk = 0; kk < 2; ++kk)
                    acc[m][n] = __builtin_amdgcn_mfma_f32_16x16x32_bf16(af[m][kk], bf[n][kk], acc[m][n], 0, 0, 0);
        __builtin_amdgcn_s_setprio(0);
        asm volatile("s_barrier" ::: "memory");

        // ---- phase 2: read B-high; stage 3; MFMA n=2,3; per-K-tile vmcnt refresh ----
        short8 bg[2][2];
#pragma unroll
        for (int n = 0; n < 2; ++n)
#pragma unroll
            for (int kk = 0; kk < 2; ++kk)
                bg[n][kk] = *(const short8*)(sb + A_BYTES + (wn * 4 + 2 + n) * 2048 + kk * 1024 + lane * 16);
        if (do_stage) { stageA(sw, kt2, 3); stageB(sw, kt2, 0); stageB(sw, kt2, 1); }
        asm volatile("s_barrier" ::: "memory");
        __builtin_amdgcn_s_setprio(1);
#pragma unroll
        for (int m = 0; m < 4; ++m)
#pragma unroll
            for (int n = 0; n < 2; ++n)
#pragma unroll
                for (int kk = 0; kk < 2; ++kk)
                    acc[m][2 + n] = __builtin_amdgcn_mfma_f32_16x16x32_bf16(af[m][kk], bg[n][kk], acc[m][2 + n], 0, 0, 0);
        __builtin_amdgcn_s_setprio(0);
        if (t + 2 < NKT)      { asm volatile("s_waitcnt vmcnt(6)" ::: "memory"); }  // t+1 landed; t+2 in flight
        else if (t + 1 < NKT) { asm volatile("s_waitcnt vmcnt(0)" ::: "memory"); }  // tail: drain for last K-tile
        asm volatile("s_barrier" ::: "memory");

        rb = rb + 1; if (rb == 3) rb = 0;
    }

    // epilogue: C/D layout col = lane&15, row = (lane>>4)*4 + reg  [verified rounds 3/7]
#pragma unroll
    for (int m = 0; m < 4; ++m)
#pragma unroll
        for (int n = 0; n < 4; ++n)
#pragma unroll
            for (int rg = 0; rg < 4; ++rg) {
                int rr = m0 + wm * 64 + m * 16 + (lane >> 4) * 4 + rg;
                int cc = n0 + wn * 64 + n * 16 + (lane & 15);
                C[(size_t)rr * NDIM + cc] = acc[m][n][rg];
            }
}

extern "C" void kernel_launch(void* const* d_in, const int* in_sizes, int n_in,
                              void* d_out, int out_size, void* d_ws, size_t ws_size,
                              hipStream_t stream) {
    const float* x     = (const float*)d_in[0];   // [8192][3072] f32
    const float* V     = (const float*)d_in[1];   // [3072][3072] f32
    const float* alpha = (const float*)d_in[2];   // [3072] f32
    float* out = (float*)d_out;                   // [8192][3072] f32

    // ws layout: a[3072] f32 | x_bf16 [8192*3072] | W_bf16 [3072*3072]
    float* a_ws = (float*)d_ws;
    unsigned short* xb = (unsigned short*)((char*)d_ws + 16384);
    unsigned short* Wb = (unsigned short*)((char*)d_ws + 16384 + (size_t)BATCHN * NDIM * 2);

    hipLaunchKernelGGL(dykstra_kernel, dim3(1), dim3(64), 0, stream, alpha, a_ws);
    hipLaunchKernelGGL(build_w, dim3(NDIM / 64, NDIM / 64), dim3(256), 0, stream, V, a_ws, Wb);
    hipLaunchKernelGGL(convert_x, dim3(2048), dim3(256), 0, stream, x, xb, BATCHN * NDIM);
    hipLaunchKernelGGL(gemm_bt, dim3((BATCHN / BM) * (NDIM / BN)), dim3(512), 0, stream,
                       xb, Wb, out);
}

// Round 11
// 453.033 us; speedup vs baseline: 1.1548x; 1.0053x over previous
//
#include <hip/hip_runtime.h>
#include <hip/hip_bf16.h>
#include <stdint.h>

#define NDIM 3072
#define BATCHN 8192
#define KTOP 16.0f
#define NITER 50

// ---- GEMM geometry: BM=256, BN=128, BK=64, 3-buffer, frag-read 1 tile ahead ----
#define BM 256
#define BN 128
#define BK 64
#define NKT (NDIM / BK)         // 48 K-tiles
#define A_BYTES 32768           // 256 x 64 bf16
#define BUF_BYTES 49152         // A + B per K-tile
// LDS total: 3 * 48 KB = 144 KB (1 block/CU, 8 waves)

typedef __attribute__((ext_vector_type(8))) short short8;
typedef __attribute__((ext_vector_type(4))) float floatx4;
typedef __attribute__((ext_vector_type(4))) unsigned short ushortx4;

__device__ inline unsigned short f2bf(float f) {
    __hip_bfloat16 h = __float2bfloat16(f);
    return *reinterpret_cast<unsigned short*>(&h);
}

// ---------------- K1: Dykstra soft-topk, reduced to scalar-D recursion ----------------
__global__ void dykstra_kernel(const float* __restrict__ alpha, float* __restrict__ a_out) {
    const int lane = threadIdx.x;  // 64 threads
    float z[48];
#pragma unroll
    for (int e = 0; e < 48; ++e) z[e] = alpha[e * 64 + lane] / 0.01f;
    float S = 0.f;
#pragma unroll
    for (int e = 0; e < 48; ++e) S += z[e];
#pragma unroll
    for (int m = 1; m < 64; m <<= 1) S += __shfl_xor(S, m, 64);

    float D = 0.f;
    for (int it = 0; it < NITER; ++it) {
        D += (KTOP - S) / (float)NDIM;
        float s2 = 0.f;
#pragma unroll
        for (int e = 0; e < 48; ++e) {
            float v = z[e] + D;
            v = v < 0.f ? 0.f : (v > 1.f ? 1.f : v);
            s2 += v;
        }
        S = s2;
#pragma unroll
        for (int m = 1; m < 64; m <<= 1) S += __shfl_xor(S, m, 64);
    }
#pragma unroll
    for (int e = 0; e < 48; ++e) {
        float v = z[e] + D;
        v = v < 0.f ? 0.f : (v > 1.f ? 1.f : v);
        a_out[e * 64 + lane] = v;
    }
}

// ---------------- K2: W[r,c] = a[(r-c)%n] * V[(r-c)%n, c] as bf16 (vectorized) ----------------
__global__ __launch_bounds__(256) void build_w(const float* __restrict__ V,
                                               const float* __restrict__ a,
                                               unsigned short* __restrict__ W) {
    __shared__ float Vs[128][64];
    __shared__ float as_[128];
    const int tid = threadIdx.x;
    const int c0 = blockIdx.x * 64;
    const int r0 = blockIdx.y * 64;
    int ib = r0 - c0 - 63;
    ib %= NDIM; if (ib < 0) ib += NDIM;

    if (tid < 128) {
        int i = ib + tid; if (i >= NDIM) i -= NDIM;
        as_[tid] = a[i];
    }
#pragma unroll
    for (int it = 0; it < 8; ++it) {
        int idx = it * 256 + tid;          // float4 units, 0..2047
        int d = idx >> 4;                  // 0..127
        int c4 = (idx & 15) * 4;
        int i = ib + d; if (i >= NDIM) i -= NDIM;
        *(floatx4*)&Vs[d][c4] = *(const floatx4*)&V[(size_t)i * NDIM + c0 + c4];
    }
    __syncthreads();

    const int c4 = (tid & 15) * 4;
    const int rr0 = tid >> 4;              // 0..15
#pragma unroll
    for (int p = 0; p < 4; ++p) {
        int rr = p * 16 + rr0;
        ushortx4 o;
#pragma unroll
        for (int j = 0; j < 4; ++j) {
            int cc = c4 + j;
            int d = rr - cc + 63;          // in [0,126]
            o[j] = f2bf(as_[d] * Vs[d][cc]);
        }
        *(ushortx4*)&W[(size_t)(r0 + rr) * NDIM + (c0 + c4)] = o;
    }
}

// ---------------- K3: x f32 -> bf16 ----------------
__global__ void convert_x(const float* __restrict__ x, unsigned short* __restrict__ xb, int n) {
    int i = (blockIdx.x * blockDim.x + threadIdx.x) * 4;
    const int stride = gridDim.x * blockDim.x * 4;
    for (; i < n; i += stride) {
        floatx4 v = *(const floatx4*)(x + i);
        ushortx4 o;
        o[0] = f2bf(v[0]); o[1] = f2bf(v[1]); o[2] = f2bf(v[2]); o[3] = f2bf(v[3]);
        *(ushortx4*)(xb + i) = o;
    }
}

// ---------------- K4: 3-buffer bf16 GEMM with 1-tile-ahead frag prefetch ----------------
// Per K-tile t: MFMA(cur regs) || stage t+2 -> buf[(t+2)%3] ; vmcnt(6) ; barrier ;
// ds_read next regs <- tile t+1 from buf[(t+1)%3]. The reads sit one tile (and one
// barrier) ahead of their consuming MFMAs -> LDS latency hidden; compiler inserts
// fine-grained lgkmcnt at use. One barrier per K-tile. Lane-ordered 1KB LDS cells
// (0 conflicts, verified R7/R9). vmcnt ledger: at tile t's wait, outstanding =
// {t+1's 6, t+2's 6}; vmcnt(6) retires t+1's; barrier makes it collective before
// any wave reads tile t+1. Tail: vmcnt(0) at t=NKT-2.
__global__ __launch_bounds__(512, 2) void gemm_bt(const unsigned short* __restrict__ A,
                                                  const unsigned short* __restrict__ B,
                                                  float* __restrict__ C) {
    __shared__ __align__(16) char lds[3 * BUF_BYTES];   // 144 KB

    // XCD-chunked swizzle, tn-fastest (low-FETCH ordering, verified R9). 768 % 8 == 0.
    const int bid = blockIdx.x;
    const int swz = (bid & 7) * 96 + (bid >> 3);
    const int tm = swz / 24, tn = swz % 24;     // 32 x 24 tiles
    const int m0 = tm * BM, n0 = tn * BN;

    const int tid = threadIdx.x;
    const int lane = tid & 63;
    const int wid = tid >> 6;     // 8 waves: 4 (M) x 2 (N)
    const int wm = wid >> 1;      // 0..3 -> 64 rows each
    const int wn = wid & 1;       // 0..1 -> 64 cols each

    const unsigned short* Ab = A + (size_t)m0 * NDIM;
    const unsigned short* Bb = B + (size_t)n0 * NDIM;

    auto stageA = [&](char* sw, int kt, int i) {   // i in 0..3, cell c = wid*4+i
        int c = wid * 4 + i;
        int b = c >> 1, kk = c & 1;
        const unsigned short* g = Ab + (size_t)(b * 16 + (lane & 15)) * NDIM + kt + kk * 32 + (lane >> 4) * 8;
        __builtin_amdgcn_global_load_lds(
            (const __attribute__((address_space(1))) unsigned int*)g,
            (__attribute__((address_space(3))) unsigned int*)(sw + c * 1024 + lane * 16),
            16, 0, 0);
    };
    auto stageB = [&](char* sw, int kt, int i) {   // i in 0..1, cell c = wid*2+i
        int c = wid * 2 + i;
        int b = c >> 1, kk = c & 1;
        const unsigned short* g = Bb + (size_t)(b * 16 + (lane & 15)) * NDIM + kt + kk * 32 + (lane >> 4) * 8;
        __builtin_amdgcn_global_load_lds(
            (const __attribute__((address_space(1))) unsigned int*)g,
            (__attribute__((address_space(3))) unsigned int*)(sw + A_BYTES + c * 1024 + lane * 16),
            16, 0, 0);
    };

#define STAGE_TILE(SW, KT)  do { \
        stageA(SW, KT, 0); stageA(SW, KT, 1); stageA(SW, KT, 2); stageA(SW, KT, 3); \
        stageB(SW, KT, 0); stageB(SW, KT, 1); } while (0)

#define READ_FRAGS(AF, BF, SB)  do { \
        _Pragma("unroll") \
        for (int m_ = 0; m_ < 4; ++m_) \
            _Pragma("unroll") \
            for (int kk_ = 0; kk_ < 2; ++kk_) \
                AF[m_][kk_] = *(const short8*)((SB) + (wm * 4 + m_) * 2048 + kk_ * 1024 + lane * 16); \
        _Pragma("unroll") \
        for (int n_ = 0; n_ < 4; ++n_) \
            _Pragma("unroll") \
            for (int kk_ = 0; kk_ < 2; ++kk_) \
                BF[n_][kk_] = *(const short8*)((SB) + A_BYTES + (wn * 4 + n_) * 2048 + kk_ * 1024 + lane * 16); } while (0)

#define MFMA_CLUSTER(AF, BF)  do { \
        __builtin_amdgcn_s_setprio(1); \
        _Pragma("unroll") \
        for (int kk_ = 0; kk_ < 2; ++kk_) \
            _Pragma("unroll") \
            for (int m_ = 0; m_ < 4; ++m_) \
                _Pragma("unroll") \
                for (int n_ = 0; n_ < 4; ++n_) \
                    acc[m_][n_] = __builtin_amdgcn_mfma_f32_16x16x32_bf16(AF[m_][kk_], BF[n_][kk_], acc[m_][n_], 0, 0, 0); \
        __builtin_amdgcn_s_setprio(0); } while (0)

#define TILE_BODY(T, AF_CUR, BF_CUR, AF_NXT, BF_NXT)  do { \
        MFMA_CLUSTER(AF_CUR, BF_CUR); \
        if ((T) + 2 < NKT) { STAGE_TILE(stg, ((T) + 2) * BK); } \
        if ((T) + 2 < NKT)      { asm volatile("s_waitcnt vmcnt(6)" ::: "memory"); } \
        else if ((T) + 1 < NKT) { asm volatile("s_waitcnt vmcnt(0)" ::: "memory"); } \
        asm volatile("s_barrier" ::: "memory"); \
        if ((T) + 1 < NKT) { READ_FRAGS(AF_NXT, BF_NXT, nxt); } \
        char* tmp_ = cur; cur = nxt; nxt = stg; stg = tmp_; } while (0)

    floatx4 acc[4][4];
#pragma unroll
    for (int i = 0; i < 4; ++i)
#pragma unroll
        for (int j = 0; j < 4; ++j) acc[i][j] = {0.f, 0.f, 0.f, 0.f};

    short8 afP[4][2], bfP[4][2], afQ[4][2], bfQ[4][2];

    char* cur = lds;                    // tile t   (frags already in regs)
    char* nxt = lds + BUF_BYTES;        // tile t+1 (ds_read source)
    char* stg = lds + 2 * BUF_BYTES;    // tile t+2 (stage dest)

    // prologue: stage tiles 0,1; wait tile 0 collectively; read tile-0 frags -> P
    STAGE_TILE(cur, 0);
    STAGE_TILE(nxt, BK);
    asm volatile("s_waitcnt vmcnt(6)" ::: "memory");
    asm volatile("s_barrier" ::: "memory");
    READ_FRAGS(afP, bfP, cur);

    for (int it = 0; it < NKT / 2; ++it) {
        const int t0 = 2 * it;
        TILE_BODY(t0,     afP, bfP, afQ, bfQ);
        TILE_BODY(t0 + 1, afQ, bfQ, afP, bfP);
    }

#undef TILE_BODY
#undef MFMA_CLUSTER
#undef READ_FRAGS
#undef STAGE_TILE

    // epilogue: C/D layout col = lane&15, row = (lane>>4)*4 + reg  [verified R3/R7/R9]
#pragma unroll
    for (int m = 0; m < 4; ++m)
#pragma unroll
        for (int n = 0; n < 4; ++n)
#pragma unroll
            for (int rg = 0; rg < 4; ++rg) {
                int rr = m0 + wm * 64 + m * 16 + (lane >> 4) * 4 + rg;
                int cc = n0 + wn * 64 + n * 16 + (lane & 15);
                C[(size_t)rr * NDIM + cc] = acc[m][n][rg];
            }
}

extern "C" void kernel_launch(void* const* d_in, const int* in_sizes, int n_in,
                              void* d_out, int out_size, void* d_ws, size_t ws_size,
                              hipStream_t stream) {
    const float* x     = (const float*)d_in[0];   // [8192][3072] f32
    const float* V     = (const float*)d_in[1];   // [3072][3072] f32
    const float* alpha = (const float*)d_in[2];   // [3072] f32
    float* out = (float*)d_out;                   // [8192][3072] f32

    // ws layout: a[3072] f32 | x_bf16 [8192*3072] | W_bf16 [3072*3072]
    float* a_ws = (float*)d_ws;
    unsigned short* xb = (unsigned short*)((char*)d_ws + 16384);
    unsigned short* Wb = (unsigned short*)((char*)d_ws + 16384 + (size_t)BATCHN * NDIM * 2);

    hipLaunchKernelGGL(dykstra_kernel, dim3(1), dim3(64), 0, stream, alpha, a_ws);
    hipLaunchKernelGGL(build_w, dim3(NDIM / 64, NDIM / 64), dim3(256), 0, stream, V, a_ws, Wb);
    hipLaunchKernelGGL(convert_x, dim3(2048), dim3(256), 0, stream, x, xb, BATCHN * NDIM);
    hipLaunchKernelGGL(gemm_bt, dim3((BATCHN / BM) * (NDIM / BN)), dim3(512), 0, stream,
                       xb, Wb, out);
}